// Round 2
// baseline (631.574 us; speedup 1.0000x reference)
//
#include <hip/hip_runtime.h>

// LSTM B=4096, T=2048, H=15. 32 lanes per batch element:
//   half 0 (lanes 0-15): unit u computes gate rows i (u), f (15+u)
//   half 1 (lanes 16-31): unit u computes gate rows g (30+u), o (45+u)
// -> 30 W_hh weights/lane (register resident), 262144 threads = 2 waves/SIMD.
// Cross-half exchange of 2 activated gates via ds_swizzle xor-16.
// h broadcast within the 32-lane group via LDS (1 write + 4x b128 reads,
// same-wave producer/consumer, DS pipe in-order per wave).

#define HID 15
#define T_LEN 2048
#define B_TOT 4096

__global__ __launch_bounds__(256, 2) void lstm_seq_kernel(
    const float* __restrict__ x,      // (B, T)
    const float* __restrict__ W_ih,   // (60, 1)
    const float* __restrict__ W_hh,   // (60, 15)
    const float* __restrict__ b_ih,   // (60,)
    const float* __restrict__ b_hh,   // (60,)
    const float* __restrict__ W_lin,  // (1, 15)
    const float* __restrict__ b_lin,  // (1,)
    float* __restrict__ out)          // (B, T)
{
    __shared__ __align__(16) float lds_h[8][16];   // [element in block][unit]

    const int tid = threadIdx.x;
    const int grp = tid >> 5;               // element within block (0..7)
    const int el  = tid & 31;               // lane within element group
    const int hf  = el >> 4;                // 0: gates i,f   1: gates g,o
    const int sub = el & 15;
    const int u   = (sub < HID) ? sub : (HID - 1);  // lane 15 duplicates unit 14
    const int b   = blockIdx.x * 8 + grp;

    const int row0 = hf * 2 * HID + u;      // i-row or g-row
    const int row1 = row0 + HID;            // f-row or o-row

    // ---- register-resident weights (30 + 15 + misc ~ fits 2-wave budget) ----
    float w0[HID], w1[HID];
#pragma unroll
    for (int k = 0; k < HID; ++k) {
        w0[k] = W_hh[row0 * HID + k];
        w1[k] = W_hh[row1 * HID + k];
    }
    const float wih0 = W_ih[row0], wih1 = W_ih[row1];
    const float bia0 = b_ih[row0] + b_hh[row0];
    const float bia1 = b_ih[row1] + b_hh[row1];

    float wlin[HID];
#pragma unroll
    for (int k = 0; k < HID; ++k) wlin[k] = W_lin[k];
    const float blin = b_lin[0];

    // activation of gate0: sigmoid (i) on half 0, tanh (g) on half 1
    //   a = fma(m0, rcp(1 + exp2(g * s0)), d0)
    const float LOG2E = 1.44269504088896341f;
    const float s0 = hf ? (-2.0f * LOG2E) : (-LOG2E);
    const float m0 = hf ? 2.0f : 1.0f;
    const float d0 = hf ? -1.0f : 0.0f;
    // gate1 (f or o) is always sigmoid.

    float c = 0.0f;
    float hk[16];
#pragma unroll
    for (int k = 0; k < 16; ++k) hk[k] = 0.0f;

    const float4* __restrict__ x4 = (const float4*)(x + (size_t)b * T_LEN);
    float4* __restrict__ o4       = (float4*)(out + (size_t)b * T_LEN);

    float4 xv = x4[0];
    for (int t0 = 0; t0 < T_LEN / 4; ++t0) {
        // prefetch next x vector (uniform address; hides under 4 steps of compute)
        const int tn = (t0 + 1 < T_LEN / 4) ? (t0 + 1) : t0;
        const float4 xnext = x4[tn];
        float ov[4];
#pragma unroll
        for (int s = 0; s < 4; ++s) {
            const float xt = (s == 0) ? xv.x : (s == 1) ? xv.y : (s == 2) ? xv.z : xv.w;

            // two gate rows for this lane
            float g0 = fmaf(xt, wih0, bia0);
            float g1 = fmaf(xt, wih1, bia1);
#pragma unroll
            for (int k = 0; k < HID; ++k) {
                g0 = fmaf(hk[k], w0[k], g0);
                g1 = fmaf(hk[k], w1[k], g1);
            }

            // activations: a0 = sig(i) or tanh(g); a1 = sig(f) or sig(o)
            const float r0 = __builtin_amdgcn_rcpf(1.0f + __builtin_amdgcn_exp2f(g0 * s0));
            const float a0 = fmaf(m0, r0, d0);
            const float a1 = __builtin_amdgcn_rcpf(1.0f + __builtin_amdgcn_exp2f(g1 * -LOG2E));

            // exchange activated gates across the half boundary (xor 16, and=0x1F)
            const float b0 = __int_as_float(__builtin_amdgcn_ds_swizzle(__float_as_int(a0), 0x401F));
            const float b1 = __int_as_float(__builtin_amdgcn_ds_swizzle(__float_as_int(a1), 0x401F));

            // half0: a0=si a1=sf b0=tg b1=so   half1: a0=tg a1=so b0=si b1=sf
            const float sfe = hf ? b1 : a1;          // sigmoid(f)
            const float soe = hf ? a1 : b1;          // sigmoid(o)
            c = fmaf(sfe, c, a0 * b0);               // a0*b0 = si*tg (commutative)
            const float tc = fmaf(2.0f,
                __builtin_amdgcn_rcpf(1.0f + __builtin_amdgcn_exp2f(c * (-2.0f * LOG2E))),
                -1.0f);
            const float hl = soe * tc;               // h for unit u (bit-identical on both halves)

            // broadcast h within the 32-lane group (same wave -> DS in-order)
            lds_h[grp][sub] = hl;                    // lane15 writes dup of h14 to scratch slot
            const float4 h0 = *(const float4*)&lds_h[grp][0];
            const float4 h1 = *(const float4*)&lds_h[grp][4];
            const float4 h2 = *(const float4*)&lds_h[grp][8];
            const float4 h3 = *(const float4*)&lds_h[grp][12];
            hk[0]  = h0.x; hk[1]  = h0.y; hk[2]  = h0.z; hk[3]  = h0.w;
            hk[4]  = h1.x; hk[5]  = h1.y; hk[6]  = h1.z; hk[7]  = h1.w;
            hk[8]  = h2.x; hk[9]  = h2.y; hk[10] = h2.z; hk[11] = h2.w;
            hk[12] = h3.x; hk[13] = h3.y; hk[14] = h3.z; hk[15] = h3.w;

            // output projection (redundant across lanes; lane 0 stores)
            float o = blin;
#pragma unroll
            for (int k = 0; k < HID; ++k) o = fmaf(hk[k], wlin[k], o);
            ov[s] = o;
        }
        if (el == 0) {
            o4[t0] = make_float4(ov[0], ov[1], ov[2], ov[3]);
        }
        xv = xnext;
    }
}

extern "C" void kernel_launch(void* const* d_in, const int* in_sizes, int n_in,
                              void* d_out, int out_size, void* d_ws, size_t ws_size,
                              hipStream_t stream) {
    const float* x     = (const float*)d_in[0];
    const float* W_ih  = (const float*)d_in[1];
    const float* W_hh  = (const float*)d_in[2];
    const float* b_ih  = (const float*)d_in[3];
    const float* b_hh  = (const float*)d_in[4];
    const float* W_lin = (const float*)d_in[5];
    const float* b_lin = (const float*)d_in[6];
    float* out = (float*)d_out;

    dim3 grid(B_TOT / 8);    // 512 blocks (8 elements/block)
    dim3 block(256);         // 8 groups of 32 lanes; 2048 waves = 2 waves/SIMD
    lstm_seq_kernel<<<grid, block, 0, stream>>>(x, W_ih, W_hh, b_ih, b_hh,
                                                W_lin, b_lin, out);
}

// Round 3
// 585.893 us; speedup vs baseline: 1.0780x; 1.0780x over previous
//
#include <hip/hip_runtime.h>

// LSTM B=4096, T=2048, H=15. 32 lanes per batch element:
//   half 0 (lanes 0-15): unit u computes gate rows i (u), f (15+u)
//   half 1 (lanes 16-31): unit u computes gate rows g (30+u), o (45+u)
// Cross-half exchange of activated gates via ds_swizzle xor-16.
// h broadcast within 32-lane group via LDS; out-projection via butterfly
// reduce (1 mul + 4 swizzle-adds) overlapped with the broadcast round-trip.
// amdgpu_waves_per_eu(2,2): target exactly 2 waves/SIMD -> 256-VGPR budget,
// keeps all weights register-resident (R1 spilled at VGPR=64).

#define HID 15
#define T_LEN 2048
#define B_TOT 4096

__global__ __launch_bounds__(256) __attribute__((amdgpu_waves_per_eu(2, 2)))
void lstm_seq_kernel(
    const float* __restrict__ x,      // (B, T)
    const float* __restrict__ W_ih,   // (60, 1)
    const float* __restrict__ W_hh,   // (60, 15)
    const float* __restrict__ b_ih,   // (60,)
    const float* __restrict__ b_hh,   // (60,)
    const float* __restrict__ W_lin,  // (1, 15)
    const float* __restrict__ b_lin,  // (1,)
    float* __restrict__ out)          // (B, T)
{
    __shared__ __align__(16) float lds_h[8][16];   // [element in block][unit]

    const int tid = threadIdx.x;
    const int grp = tid >> 5;               // element within block (0..7)
    const int el  = tid & 31;               // lane within element group
    const int hf  = el >> 4;                // 0: gates i,f   1: gates g,o
    const int sub = el & 15;
    const int u   = (sub < HID) ? sub : (HID - 1);  // lane 15 duplicates unit 14
    const int b   = blockIdx.x * 8 + grp;

    const int row0 = hf * 2 * HID + u;      // i-row or g-row
    const int row1 = row0 + HID;            // f-row or o-row

    float w0[HID], w1[HID];
#pragma unroll
    for (int k = 0; k < HID; ++k) {
        w0[k] = W_hh[row0 * HID + k];
        w1[k] = W_hh[row1 * HID + k];
    }
    const float wih0 = W_ih[row0], wih1 = W_ih[row1];
    const float bia0 = b_ih[row0] + b_hh[row0];
    const float bia1 = b_ih[row1] + b_hh[row1];
    // out-projection weight for this lane's unit; lane 15 masked to 0 so the
    // butterfly reduce doesn't double-count unit 14.
    const float wlin_m = (sub < HID) ? W_lin[sub] : 0.0f;
    const float blin = b_lin[0];

    const float LOG2E = 1.44269504088896341f;
    const float s0 = hf ? (-2.0f * LOG2E) : (-LOG2E);   // tanh | sigmoid scale
    const float m0 = hf ? 2.0f : 1.0f;
    const float d0 = hf ? -1.0f : 0.0f;

    float c = 0.0f;
    float4 hA = make_float4(0.f, 0.f, 0.f, 0.f);
    float4 hB = hA, hC = hA, hD = hA;

    const float4* __restrict__ x4 = (const float4*)(x + (size_t)b * T_LEN);
    float4* __restrict__ o4       = (float4*)(out + (size_t)b * T_LEN);

    for (int t0 = 0; t0 < T_LEN / 4; ++t0) {
        const float4 xv = x4[t0];
        float ov[4];
#pragma unroll
        for (int s = 0; s < 4; ++s) {
            const float xt = (s == 0) ? xv.x : (s == 1) ? xv.y : (s == 2) ? xv.z : xv.w;

            // ---- two gate rows, dual accumulators (even/odd k) ----
            float g0a = bia0, g0b = 0.0f, g1a = bia1, g1b = 0.0f;
            g0a = fmaf(hA.x, w0[0],  g0a); g0b = fmaf(hA.y, w0[1],  g0b);
            g0a = fmaf(hA.z, w0[2],  g0a); g0b = fmaf(hA.w, w0[3],  g0b);
            g0a = fmaf(hB.x, w0[4],  g0a); g0b = fmaf(hB.y, w0[5],  g0b);
            g0a = fmaf(hB.z, w0[6],  g0a); g0b = fmaf(hB.w, w0[7],  g0b);
            g0a = fmaf(hC.x, w0[8],  g0a); g0b = fmaf(hC.y, w0[9],  g0b);
            g0a = fmaf(hC.z, w0[10], g0a); g0b = fmaf(hC.w, w0[11], g0b);
            g0a = fmaf(hD.x, w0[12], g0a); g0b = fmaf(hD.y, w0[13], g0b);
            g0a = fmaf(hD.z, w0[14], g0a);
            g1a = fmaf(hA.x, w1[0],  g1a); g1b = fmaf(hA.y, w1[1],  g1b);
            g1a = fmaf(hA.z, w1[2],  g1a); g1b = fmaf(hA.w, w1[3],  g1b);
            g1a = fmaf(hB.x, w1[4],  g1a); g1b = fmaf(hB.y, w1[5],  g1b);
            g1a = fmaf(hB.z, w1[6],  g1a); g1b = fmaf(hB.w, w1[7],  g1b);
            g1a = fmaf(hC.x, w1[8],  g1a); g1b = fmaf(hC.y, w1[9],  g1b);
            g1a = fmaf(hC.z, w1[10], g1a); g1b = fmaf(hC.w, w1[11], g1b);
            g1a = fmaf(hD.x, w1[12], g1a); g1b = fmaf(hD.y, w1[13], g1b);
            g1a = fmaf(hD.z, w1[14], g1a);
            const float g0 = fmaf(xt, wih0, g0a + g0b);
            const float g1 = fmaf(xt, wih1, g1a + g1b);

            // ---- activations: a0 = sig(i) | tanh(g); a1 = sig(f) | sig(o) ----
            const float r0 = __builtin_amdgcn_rcpf(1.0f + __builtin_amdgcn_exp2f(g0 * s0));
            const float a0 = fmaf(m0, r0, d0);
            const float a1 = __builtin_amdgcn_rcpf(1.0f + __builtin_amdgcn_exp2f(g1 * -LOG2E));

            // ---- exchange across the half boundary (xor 16 within 32 lanes) ----
            const float b0 = __int_as_float(__builtin_amdgcn_ds_swizzle(__float_as_int(a0), 0x401F));
            const float b1 = __int_as_float(__builtin_amdgcn_ds_swizzle(__float_as_int(a1), 0x401F));

            // half0: a0=si a1=sf b0=tg b1=so   half1: a0=tg a1=so b0=si b1=sf
            const float sfe = hf ? b1 : a1;
            const float soe = hf ? a1 : b1;
            c = fmaf(sfe, c, a0 * b0);           // a0*b0 = si*tg (commutative)
            const float tc = fmaf(2.0f,
                __builtin_amdgcn_rcpf(1.0f + __builtin_amdgcn_exp2f(c * (-2.0f * LOG2E))),
                -1.0f);
            const float hl = soe * tc;           // identical on both halves

            // ---- h broadcast (LDS) + out-projection butterfly (overlapped) ----
            lds_h[grp][sub] = hl;                // same-wave producer/consumer
            hA = *(const float4*)&lds_h[grp][0];
            hB = *(const float4*)&lds_h[grp][4];
            hC = *(const float4*)&lds_h[grp][8];
            hD = *(const float4*)&lds_h[grp][12];

            float red = hl * wlin_m;             // lane's own unit contribution
            red += __int_as_float(__builtin_amdgcn_ds_swizzle(__float_as_int(red), 0x041F));
            red += __int_as_float(__builtin_amdgcn_ds_swizzle(__float_as_int(red), 0x081F));
            red += __int_as_float(__builtin_amdgcn_ds_swizzle(__float_as_int(red), 0x101F));
            red += __int_as_float(__builtin_amdgcn_ds_swizzle(__float_as_int(red), 0x201F));
            ov[s] = red + blin;
        }
        if (el == 0) {
            o4[t0] = make_float4(ov[0], ov[1], ov[2], ov[3]);
        }
    }
}

extern "C" void kernel_launch(void* const* d_in, const int* in_sizes, int n_in,
                              void* d_out, int out_size, void* d_ws, size_t ws_size,
                              hipStream_t stream) {
    const float* x     = (const float*)d_in[0];
    const float* W_ih  = (const float*)d_in[1];
    const float* W_hh  = (const float*)d_in[2];
    const float* b_ih  = (const float*)d_in[3];
    const float* b_hh  = (const float*)d_in[4];
    const float* W_lin = (const float*)d_in[5];
    const float* b_lin = (const float*)d_in[6];
    float* out = (float*)d_out;

    dim3 grid(B_TOT / 8);    // 512 blocks (8 elements/block)
    dim3 block(256);         // 8 groups of 32 lanes; 2048 waves = 2 waves/SIMD
    lstm_seq_kernel<<<grid, block, 0, stream>>>(x, W_ih, W_hh, b_ih, b_hh,
                                                W_lin, b_lin, out);
}

// Round 4
// 567.157 us; speedup vs baseline: 1.1136x; 1.0330x over previous
//
#include <hip/hip_runtime.h>

// LSTM B=4096, T=2048, H=15. 32 lanes per batch element:
//   half 0 (lanes 0-15): unit u computes gate rows i (u), f (15+u)
//   half 1 (lanes 16-31): unit u computes gate rows g (30+u), o (45+u)
// Both gate rows accumulate in ONE packed chain (v_pk_fma_f32, full-rate fp32).
// Cross-half exchange of 2 activated gates via ds_swizzle xor-16 (only DS
// traffic besides the h broadcast: 2 swizzle + 1 write + 4 read per step).
// R2 lesson: NO dependent-DS-chain reductions (butterfly put ~400cy on the
// recurrence path). Out-projection = packed FMAs on broadcast h (off-chain).

#define HID 15
#define T_LEN 2048
#define B_TOT 4096

typedef float v2f __attribute__((ext_vector_type(2)));

__device__ __forceinline__ v2f fma2(v2f a, v2f b, v2f c) {
    return __builtin_elementwise_fma(a, b, c);
}

__global__ __launch_bounds__(256) __attribute__((amdgpu_waves_per_eu(2, 2)))
void lstm_seq_kernel(
    const float* __restrict__ x,      // (B, T)
    const float* __restrict__ W_ih,   // (60, 1)
    const float* __restrict__ W_hh,   // (60, 15)
    const float* __restrict__ b_ih,   // (60,)
    const float* __restrict__ b_hh,   // (60,)
    const float* __restrict__ W_lin,  // (1, 15)
    const float* __restrict__ b_lin,  // (1,)
    float* __restrict__ out)          // (B, T)
{
    __shared__ __align__(16) float lds_h[8][16];   // [element in block][unit]

    const int tid = threadIdx.x;
    const int grp = tid >> 5;               // element within block (0..7)
    const int el  = tid & 31;               // lane within element group
    const int hf  = el >> 4;                // 0: gates i,f   1: gates g,o
    const int sub = el & 15;
    const int u   = (sub < HID) ? sub : (HID - 1);  // lane 15 duplicates unit 14
    const int b   = blockIdx.x * 8 + grp;

    const int row0 = hf * 2 * HID + u;      // i-row or g-row
    const int row1 = row0 + HID;            // f-row or o-row

    // ---- packed weights: wp[k] = { W_hh[row0][k], W_hh[row1][k] } ----
    v2f wp[HID];
#pragma unroll
    for (int k = 0; k < HID; ++k) {
        wp[k].x = W_hh[row0 * HID + k];
        wp[k].y = W_hh[row1 * HID + k];
    }
    v2f wih; wih.x = W_ih[row0]; wih.y = W_ih[row1];
    v2f bia; bia.x = b_ih[row0] + b_hh[row0]; bia.y = b_ih[row1] + b_hh[row1];

    // packed out-projection weights: wl[j] = {W_lin[2j], W_lin[2j+1]}, pad 0
    v2f wl[8];
#pragma unroll
    for (int j = 0; j < 8; ++j) {
        wl[j].x = W_lin[2 * j];
        wl[j].y = (2 * j + 1 < HID) ? W_lin[2 * j + 1] : 0.0f;
    }
    const float blin = b_lin[0];

    const float LOG2E = 1.44269504088896341f;
    // gate0 activation: sigmoid (half0) | tanh (half1); gate1 always sigmoid
    const float s0 = hf ? (-2.0f * LOG2E) : (-LOG2E);
    const float m0 = hf ? 2.0f : 1.0f;
    const float d0 = hf ? -1.0f : 0.0f;
    v2f sv; sv.x = s0; sv.y = -LOG2E;       // packed exp2 scales for g0,g1

    float c = 0.0f;
    float4 hA = make_float4(0.f, 0.f, 0.f, 0.f);
    float4 hB = hA, hC = hA, hD = hA;

    const float4* __restrict__ x4 = (const float4*)(x + (size_t)b * T_LEN);
    float4* __restrict__ o4       = (float4*)(out + (size_t)b * T_LEN);

    float4 xv = x4[0];
    for (int t0 = 0; t0 < T_LEN / 4; ++t0) {
        const int tn = (t0 + 1 < T_LEN / 4) ? (t0 + 1) : t0;
        const float4 xnext = x4[tn];        // prefetch; hides under 4 steps
        float ov[4];
#pragma unroll
        for (int s = 0; s < 4; ++s) {
            const float xt = (s == 0) ? xv.x : (s == 1) ? xv.y : (s == 2) ? xv.z : xv.w;

            // ---- both gate rows in one packed dual-accumulator chain ----
            v2f ae = bia;                   // even k
            v2f ao; ao.x = 0.0f; ao.y = 0.0f;   // odd k
            ae = fma2((v2f){hA.x, hA.x}, wp[0],  ae);
            ao = fma2((v2f){hA.y, hA.y}, wp[1],  ao);
            ae = fma2((v2f){hA.z, hA.z}, wp[2],  ae);
            ao = fma2((v2f){hA.w, hA.w}, wp[3],  ao);
            ae = fma2((v2f){hB.x, hB.x}, wp[4],  ae);
            ao = fma2((v2f){hB.y, hB.y}, wp[5],  ao);
            ae = fma2((v2f){hB.z, hB.z}, wp[6],  ae);
            ao = fma2((v2f){hB.w, hB.w}, wp[7],  ao);
            ae = fma2((v2f){hC.x, hC.x}, wp[8],  ae);
            ao = fma2((v2f){hC.y, hC.y}, wp[9],  ao);
            ae = fma2((v2f){hC.z, hC.z}, wp[10], ae);
            ao = fma2((v2f){hC.w, hC.w}, wp[11], ao);
            ae = fma2((v2f){hD.x, hD.x}, wp[12], ae);
            ao = fma2((v2f){hD.y, hD.y}, wp[13], ao);
            ae = fma2((v2f){hD.z, hD.z}, wp[14], ae);
            const v2f g = fma2((v2f){xt, xt}, wih, ae + ao);

            // ---- activations (packed mul/add, scalar trans ops) ----
            const v2f earg = g * sv;
            const float e0 = __builtin_amdgcn_exp2f(earg.x);
            const float e1 = __builtin_amdgcn_exp2f(earg.y);
            const float r0 = __builtin_amdgcn_rcpf(1.0f + e0);
            const float r1 = __builtin_amdgcn_rcpf(1.0f + e1);
            const float a0 = fmaf(m0, r0, d0);  // sig(i) | tanh(g)
            const float a1 = r1;                // sig(f) | sig(o)

            // ---- exchange across half boundary (xor 16 within 32 lanes) ----
            const float b0 = __int_as_float(__builtin_amdgcn_ds_swizzle(__float_as_int(a0), 0x401F));
            const float b1 = __int_as_float(__builtin_amdgcn_ds_swizzle(__float_as_int(a1), 0x401F));

            // half0: a0=si a1=sf b0=tg b1=so   half1: a0=tg a1=so b0=si b1=sf
            const float sfe = hf ? b1 : a1;
            const float soe = hf ? a1 : b1;
            c = fmaf(sfe, c, a0 * b0);          // a0*b0 = si*tg (commutative)
            const float tc = fmaf(2.0f,
                __builtin_amdgcn_rcpf(1.0f + __builtin_amdgcn_exp2f(c * (-2.0f * LOG2E))),
                -1.0f);
            const float hl = soe * tc;          // identical on both halves

            // ---- h broadcast via LDS (same-wave producer/consumer) ----
            lds_h[grp][sub] = hl;
            hA = *(const float4*)&lds_h[grp][0];
            hB = *(const float4*)&lds_h[grp][4];
            hC = *(const float4*)&lds_h[grp][8];
            hD = *(const float4*)&lds_h[grp][12];

            // ---- out-projection: packed FMAs on broadcast h (off-chain) ----
            v2f pa; pa.x = blin; pa.y = 0.0f;
            v2f pb; pb.x = 0.0f; pb.y = 0.0f;
            pa = fma2((v2f){hA.x, hA.y}, wl[0], pa);
            pb = fma2((v2f){hA.z, hA.w}, wl[1], pb);
            pa = fma2((v2f){hB.x, hB.y}, wl[2], pa);
            pb = fma2((v2f){hB.z, hB.w}, wl[3], pb);
            pa = fma2((v2f){hC.x, hC.y}, wl[4], pa);
            pb = fma2((v2f){hC.z, hC.w}, wl[5], pb);
            pa = fma2((v2f){hD.x, hD.y}, wl[6], pa);
            pb = fma2((v2f){hD.z, hD.w}, wl[7], pb);   // wl[7].y=0 masks hk[15]
            const v2f ps = pa + pb;
            ov[s] = ps.x + ps.y;
        }
        if (el == 0) {
            o4[t0] = make_float4(ov[0], ov[1], ov[2], ov[3]);
        }
        xv = xnext;
    }
}

extern "C" void kernel_launch(void* const* d_in, const int* in_sizes, int n_in,
                              void* d_out, int out_size, void* d_ws, size_t ws_size,
                              hipStream_t stream) {
    const float* x     = (const float*)d_in[0];
    const float* W_ih  = (const float*)d_in[1];
    const float* W_hh  = (const float*)d_in[2];
    const float* b_ih  = (const float*)d_in[3];
    const float* b_hh  = (const float*)d_in[4];
    const float* W_lin = (const float*)d_in[5];
    const float* b_lin = (const float*)d_in[6];
    float* out = (float*)d_out;

    dim3 grid(B_TOT / 8);    // 512 blocks (8 elements/block)
    dim3 block(256);         // 8 groups of 32 lanes; 2048 waves = 2 waves/SIMD
    lstm_seq_kernel<<<grid, block, 0, stream>>>(x, W_ih, W_hh, b_ih, b_hh,
                                                W_lin, b_lin, out);
}

// Round 5
// 484.349 us; speedup vs baseline: 1.3040x; 1.1710x over previous
//
#include <hip/hip_runtime.h>

// LSTM B=4096, T=2048, H=15. R4: all cross-lane via DPP (VALU pipe), zero LDS.
// 16 lanes per batch element; lane u owns unit u and computes ALL 4 of its
// gates -> cell update is fully lane-local, no gate exchange.
// h all-gather: 15x v_mov_b32_dpp row_ror:j within the 16-lane row, with
// weights PRE-ROTATED at init to match the hardware perm (self-calibrated by
// pushing the lane index through the same DPP ops -> direction-proof).
// Output projection: per-lane h*W_lin[u] + 4-op DPP butterfly reduce
// (quad_perm xor1/xor2 + row_mirror + row_half_mirror, all involutions).
// R3 lesson: the 756cy/step chain was DS-latency (swizzle+LDS bcast ~400cy);
// DPP hops are ~4cy -> chain ~150cy, kernel becomes issue-bound.

#define HID 15
#define T_LEN 2048
#define B_TOT 4096

template<int CTRL>
__device__ __forceinline__ int dpp_i(int v) {
    return __builtin_amdgcn_update_dpp(0, v, CTRL, 0xF, 0xF, true);
}
template<int CTRL>
__device__ __forceinline__ float dpp_f(float v) {
    return __int_as_float(
        __builtin_amdgcn_update_dpp(0, __float_as_int(v), CTRL, 0xF, 0xF, true));
}

__global__ __launch_bounds__(256) __attribute__((amdgpu_waves_per_eu(1, 1)))
void lstm_seq_kernel(
    const float* __restrict__ x,      // (B, T)
    const float* __restrict__ W_ih,   // (60, 1)
    const float* __restrict__ W_hh,   // (60, 15)
    const float* __restrict__ b_ih,   // (60,)
    const float* __restrict__ b_hh,   // (60,)
    const float* __restrict__ W_lin,  // (1, 15)
    const float* __restrict__ b_lin,  // (1,)
    float* __restrict__ out)          // (B, T)
{
    const int tid = threadIdx.x;
    const int sub = tid & 15;                        // lane within 16-row
    const int u   = (sub < HID) ? sub : (HID - 1);   // lane 15 dups unit 14
    const int b   = blockIdx.x * 16 + (tid >> 4);    // batch element

    // ---- self-calibrate the row_ror permutation (direction-proof) ----
    int pos[16];
    pos[0]  = sub;
    pos[1]  = dpp_i<0x121>(sub);  pos[2]  = dpp_i<0x122>(sub);
    pos[3]  = dpp_i<0x123>(sub);  pos[4]  = dpp_i<0x124>(sub);
    pos[5]  = dpp_i<0x125>(sub);  pos[6]  = dpp_i<0x126>(sub);
    pos[7]  = dpp_i<0x127>(sub);  pos[8]  = dpp_i<0x128>(sub);
    pos[9]  = dpp_i<0x129>(sub);  pos[10] = dpp_i<0x12A>(sub);
    pos[11] = dpp_i<0x12B>(sub);  pos[12] = dpp_i<0x12C>(sub);
    pos[13] = dpp_i<0x12D>(sub);  pos[14] = dpp_i<0x12E>(sub);
    pos[15] = dpp_i<0x12F>(sub);

    // ---- pre-rotated weights: wgR[j] multiplies the value arriving via
    //      rotation j (which is h[pos[j]]); pos==15 is the dup slot -> 0 ----
    const int r0 = u, r1 = HID + u, r2 = 2 * HID + u, r3 = 3 * HID + u;
    float wg0[16], wg1[16], wg2[16], wg3[16];
#pragma unroll
    for (int j = 0; j < 16; ++j) {
        const int p = pos[j];
        const bool v = (p < HID);
        wg0[j] = v ? W_hh[r0 * HID + p] : 0.0f;
        wg1[j] = v ? W_hh[r1 * HID + p] : 0.0f;
        wg2[j] = v ? W_hh[r2 * HID + p] : 0.0f;
        wg3[j] = v ? W_hh[r3 * HID + p] : 0.0f;
    }
    const float wih0 = W_ih[r0], wih1 = W_ih[r1], wih2 = W_ih[r2], wih3 = W_ih[r3];
    const float bi0 = b_ih[r0] + b_hh[r0];
    const float bi1 = b_ih[r1] + b_hh[r1];
    const float bi2 = b_ih[r2] + b_hh[r2];
    const float bi3 = b_ih[r3] + b_hh[r3];
    const float wlin_m = (sub < HID) ? W_lin[sub] : 0.0f;  // lane15 masked
    const float blin = b_lin[0];

    const float L  = 1.44269504088896341f;   // log2(e)

    float c = 0.0f, hl = 0.0f;
    const float4* __restrict__ x4 = (const float4*)(x + (size_t)b * T_LEN);
    float4* __restrict__ o4       = (float4*)(out + (size_t)b * T_LEN);

    float4 xv = x4[0];
    for (int t0 = 0; t0 < T_LEN / 4; ++t0) {
        const int tn = (t0 + 1 < T_LEN / 4) ? (t0 + 1) : t0;
        const float4 xnext = x4[tn];
        float ov[4];
#pragma unroll
        for (int s = 0; s < 4; ++s) {
            const float xt = (s == 0) ? xv.x : (s == 1) ? xv.y : (s == 2) ? xv.z : xv.w;

            // ---- h all-gather via 15 independent DPP rotates (~VALU lat) ----
            float hr[16];
            hr[0]  = hl;
            hr[1]  = dpp_f<0x121>(hl);  hr[2]  = dpp_f<0x122>(hl);
            hr[3]  = dpp_f<0x123>(hl);  hr[4]  = dpp_f<0x124>(hl);
            hr[5]  = dpp_f<0x125>(hl);  hr[6]  = dpp_f<0x126>(hl);
            hr[7]  = dpp_f<0x127>(hl);  hr[8]  = dpp_f<0x128>(hl);
            hr[9]  = dpp_f<0x129>(hl);  hr[10] = dpp_f<0x12A>(hl);
            hr[11] = dpp_f<0x12B>(hl);  hr[12] = dpp_f<0x12C>(hl);
            hr[13] = dpp_f<0x12D>(hl);  hr[14] = dpp_f<0x12E>(hl);
            hr[15] = dpp_f<0x12F>(hl);

            // ---- 4 gate rows, dual accumulators each (8 indep chains) ----
            float a0 = fmaf(xt, wih0, bi0), c0 = 0.0f;
            float a1 = fmaf(xt, wih1, bi1), c1 = 0.0f;
            float a2 = fmaf(xt, wih2, bi2), c2 = 0.0f;
            float a3 = fmaf(xt, wih3, bi3), c3 = 0.0f;
#pragma unroll
            for (int j = 0; j < 16; j += 2) {
                a0 = fmaf(hr[j], wg0[j], a0);  c0 = fmaf(hr[j+1], wg0[j+1], c0);
                a1 = fmaf(hr[j], wg1[j], a1);  c1 = fmaf(hr[j+1], wg1[j+1], c1);
                a2 = fmaf(hr[j], wg2[j], a2);  c2 = fmaf(hr[j+1], wg2[j+1], c2);
                a3 = fmaf(hr[j], wg3[j], a3);  c3 = fmaf(hr[j+1], wg3[j+1], c3);
            }
            const float g0 = a0 + c0;   // i
            const float g1 = a1 + c1;   // f
            const float g2 = a2 + c2;   // g
            const float g3 = a3 + c3;   // o

            // ---- activations (4 independent trans chains) ----
            const float si = __builtin_amdgcn_rcpf(1.0f + __builtin_amdgcn_exp2f(g0 * -L));
            const float sf = __builtin_amdgcn_rcpf(1.0f + __builtin_amdgcn_exp2f(g1 * -L));
            const float tg = fmaf(2.0f,
                __builtin_amdgcn_rcpf(1.0f + __builtin_amdgcn_exp2f(g2 * (-2.0f * L))), -1.0f);
            const float so = __builtin_amdgcn_rcpf(1.0f + __builtin_amdgcn_exp2f(g3 * -L));

            // ---- lane-local cell update ----
            c = fmaf(sf, c, si * tg);
            const float tc = fmaf(2.0f,
                __builtin_amdgcn_rcpf(1.0f + __builtin_amdgcn_exp2f(c * (-2.0f * L))), -1.0f);
            hl = so * tc;

            // ---- out-projection: DPP butterfly (involutions, off-chain) ----
            float p = hl * wlin_m;
            p += dpp_f<0x0B1>(p);   // quad_perm xor1
            p += dpp_f<0x04E>(p);   // quad_perm xor2
            p += dpp_f<0x140>(p);   // row_mirror   (quad 0<->3, 1<->2)
            p += dpp_f<0x141>(p);   // half_mirror  (quad 0<->1, 2<->3)
            ov[s] = p + blin;
        }
        if (sub == 0) {
            o4[t0] = make_float4(ov[0], ov[1], ov[2], ov[3]);
        }
        xv = xnext;
    }
}

extern "C" void kernel_launch(void* const* d_in, const int* in_sizes, int n_in,
                              void* d_out, int out_size, void* d_ws, size_t ws_size,
                              hipStream_t stream) {
    const float* x     = (const float*)d_in[0];
    const float* W_ih  = (const float*)d_in[1];
    const float* W_hh  = (const float*)d_in[2];
    const float* b_ih  = (const float*)d_in[3];
    const float* b_hh  = (const float*)d_in[4];
    const float* W_lin = (const float*)d_in[5];
    const float* b_lin = (const float*)d_in[6];
    float* out = (float*)d_out;

    dim3 grid(B_TOT / 16);   // 256 blocks of 16 elements
    dim3 block(256);         // 4 waves/block, 4 elements/wave, no LDS/barriers
    lstm_seq_kernel<<<grid, block, 0, stream>>>(x, W_ih, W_hh, b_ih, b_hh,
                                                W_lin, b_lin, out);
}